// Round 3
// baseline (253.348 us; speedup 1.0000x reference)
//
#include <hip/hip_runtime.h>

// PatchExtractor: crop-to-bbox central square + bilinear resize to 224x224 + CLIP normalize.
// img: [3,2048,2048] f32, bboxes: [N,4] i32 xyxy, out: [N,3,224,224] f32.
//
// R1/R2: 4 consecutive ox pixels per thread (224 = 56 quads/row, quads never
// straddle rows) -> 16B nontemporal stores (no L2 write-allocate pollution of
// the image working set), vertical lerp state (sy/iy0/wy/rows) shared across
// the 4 px, bbox math amortized 4x. One thread = 4 px x 3 ch.
// R2 fix: __builtin_nontemporal_store needs a native vector type, not HIP float4.

#define S      224
#define QPR    56          // quads per row
#define IMG_H  2048
#define IMG_W  2048

typedef float f32x4 __attribute__((ext_vector_type(4)));

__global__ __launch_bounds__(256) void patch_kernel(
    const float* __restrict__ img,
    const float* __restrict__ mean,
    const float* __restrict__ stdd,
    const int*   __restrict__ bboxes,
    float*       __restrict__ out)
{
    const int n    = blockIdx.y;
    const int quad = blockIdx.x * 256 + threadIdx.x;   // 56*224 = 12544 = 49*256 exact
    const int oy   = quad / QPR;
    const int ox4  = (quad - oy * QPR) * 4;

    // bbox (block-uniform; L1-cached)
    const float x0 = (float)bboxes[n * 4 + 0];
    const float y0 = (float)bboxes[n * 4 + 1];
    const float x1 = (float)bboxes[n * 4 + 2];
    const float y1 = (float)bboxes[n * 4 + 3];

    const float side  = fminf(x1 - x0, y1 - y0);
    const float basex = (x0 + x1) * 0.5f - side * 0.5f - 0.5f;
    const float basey = (y0 + y1) * 0.5f - side * 0.5f - 0.5f;
    const float invS  = 1.0f / (float)S;

    // vertical: shared by all 4 px
    float sy = fmaf((oy + 0.5f) * invS, side, basey);
    sy = fminf(fmaxf(sy, 0.0f), (float)(IMG_H - 1));
    const int   iy0 = (int)floorf(sy);
    const int   iy1 = min(iy0 + 1, IMG_H - 1);
    const float wy  = sy - (float)iy0;
    const size_t r0 = (size_t)iy0 * IMG_W;
    const size_t r1 = (size_t)iy1 * IMG_W;

    // horizontal: per-px
    int   ix0[4], ix1[4];
    float wx[4];
#pragma unroll
    for (int j = 0; j < 4; ++j) {
        float sx = fmaf((ox4 + j + 0.5f) * invS, side, basex);
        sx = fminf(fmaxf(sx, 0.0f), (float)(IMG_W - 1));
        ix0[j] = (int)floorf(sx);
        ix1[j] = min(ix0[j] + 1, IMG_W - 1);
        wx[j]  = sx - (float)ix0[j];
    }

#pragma unroll
    for (int c = 0; c < 3; ++c) {
        const float* __restrict__ p = img + (size_t)c * (IMG_H * IMG_W);
        const float m  = mean[c];
        const float sd = stdd[c];
        const float scale = 1.0f / (255.0f * sd);
        const float bias  = -m / sd;

        f32x4 o;
#pragma unroll
        for (int j = 0; j < 4; ++j) {
            const float p00 = p[r0 + ix0[j]];
            const float p01 = p[r0 + ix1[j]];
            const float p10 = p[r1 + ix0[j]];
            const float p11 = p[r1 + ix1[j]];
            const float top = fmaf(wx[j], p01 - p00, p00);
            const float bot = fmaf(wx[j], p11 - p10, p10);
            const float v   = fmaf(wy, bot - top, top);
            o[j] = fmaf(v, scale, bias);
        }

        f32x4* dst = (f32x4*)(out + (((size_t)n * 3 + c) * S + (size_t)oy) * S + ox4);
        __builtin_nontemporal_store(o, dst);
    }
}

extern "C" void kernel_launch(void* const* d_in, const int* in_sizes, int n_in,
                              void* d_out, int out_size, void* d_ws, size_t ws_size,
                              hipStream_t stream)
{
    const float* img    = (const float*)d_in[0];
    const float* mean   = (const float*)d_in[1];
    const float* stdd   = (const float*)d_in[2];
    const int*   bboxes = (const int*)d_in[3];
    float* out = (float*)d_out;

    const int N = in_sizes[3] / 4;                 // 256 boxes
    dim3 grid(S * QPR / 256, N);                   // 49 x 256 blocks
    patch_kernel<<<grid, 256, 0, stream>>>(img, mean, stdd, bboxes, out);
}